// Round 16
// baseline (141.541 us; speedup 1.0000x reference)
//
#include <hip/hip_runtime.h>

// HMM forward, LINEAR domain, power-of-2 rescaling. B=64, D=128, A=128.
// R16 = R15 FUSED into ONE kernel with flag-based producer/consumer
// streaming. R15 budget: fill 45 | pairs ~14 | quads ~7 | fwd ~20 | gaps ~15.
// The 3 stages were stream-serialized, but deps are fine-grained: fwd step S
// needs only quad S, which needs pairs 2S/2S+1. Fusing lets fwd's serial
// 33-step chain hide nearly all precompute + kills 2 launch gaps.
// - 565 blocks x 512: [0,253) pairs (R15 verbatim + flag), [253,501) quads
//   (248 blocks x 2 variants: same B, two A's), [501,565) fwd (waves 4-7
//   mirror 0-3; duplicate writes benign).
// - Flags: one per matrix slot, in ws after quad mats; zeroed by
//   hipMemsetAsync pre-launch. Producer: __syncthreads() (drains stores) ->
//   tid0 release-agent atomic store. Consumer: RELAXED agent polls -- sound
//   because consumers first-touch data lines only after the flag (release
//   wrote L2 back to IF$ before flag visible; no stale cached copies).
// - Deadlock-free: spinners (248 quads + 64 fwd = 312) < capacity (512 =
//   2 blk/CU @ 71KB LDS) -> pairs always schedulable, any dispatch order.
// - fwd STEP: flag for t+2 POLLED EARLY (relaxed load at step top), checked
//   after compute -> ~0 critical-path cost when set; prefetch issues at
//   step end (~1 step slack > L2/L3 latency).
// ws: mats 0..253 pairs, LP at 254*8192 uints, quads 256..751, flags at
// 752*8192 uints (752 words). ~24.6 MB total.

#define B_ 64
#define D_ 128
#define A_ 128

#define LP_OFF (254 * 8192)
#define QMAT 256
#define FLG_OFF (752 * 8192)

typedef _Float16 h2 __attribute__((ext_vector_type(2)));
typedef _Float16 f16x8 __attribute__((ext_vector_type(8)));
typedef float f32x4 __attribute__((ext_vector_type(4)));

__device__ __forceinline__ unsigned packrtz(float a, float b) {
    auto p = __builtin_amdgcn_cvt_pkrtz(a, b);
    return __builtin_bit_cast(unsigned, p);
}
__device__ __forceinline__ float dot2acc(unsigned e, unsigned s, float acc) {
    return __builtin_amdgcn_fdot2(__builtin_bit_cast(h2, e),
                                  __builtin_bit_cast(h2, s), acc, false);
}
__device__ __forceinline__ unsigned pkmax(unsigned a, unsigned b) {
    unsigned d;
    asm("v_pk_max_f16 %0, %1, %2" : "=v"(d) : "v"(a), "v"(b));
    return d;
}
__device__ __forceinline__ unsigned pkmul(unsigned a, unsigned b) {
    unsigned d;
    asm("v_pk_mul_f16 %0, %1, %2" : "=v"(d) : "v"(a), "v"(b));
    return d;
}
__device__ __forceinline__ unsigned pkmax4(uint4 u) {
    return pkmax(pkmax(u.x, u.y), pkmax(u.z, u.w));
}

template <int CTRL>
__device__ __forceinline__ float dpp_mov_self(float x) {
    return __int_as_float(__builtin_amdgcn_update_dpp(
        __float_as_int(x), __float_as_int(x), CTRL, 0xF, 0xF, false));
}
template <int CTRL>
__device__ __forceinline__ float dpp_mov_zero(float x) {
    return __int_as_float(__builtin_amdgcn_update_dpp(
        0, __float_as_int(x), CTRL, 0xF, 0xF, true));
}
__device__ __forceinline__ float wave_max_bcast(float x) {
    x = fmaxf(x, dpp_mov_self<0x111>(x));
    x = fmaxf(x, dpp_mov_self<0x112>(x));
    x = fmaxf(x, dpp_mov_self<0x114>(x));
    x = fmaxf(x, dpp_mov_self<0x118>(x));
    x = fmaxf(x, dpp_mov_self<0x142>(x));
    x = fmaxf(x, dpp_mov_self<0x143>(x));
    return __int_as_float(__builtin_amdgcn_readlane(__float_as_int(x), 63));
}
__device__ __forceinline__ float wave_sum_bcast(float x) {
    x += dpp_mov_zero<0x111>(x);
    x += dpp_mov_zero<0x112>(x);
    x += dpp_mov_zero<0x114>(x);
    x += dpp_mov_zero<0x118>(x);
    x += dpp_mov_zero<0x142>(x);
    x += dpp_mov_zero<0x143>(x);
    return __int_as_float(__builtin_amdgcn_readlane(__float_as_int(x), 63));
}

__device__ __forceinline__ f32x4 mfma16(uint4 a, uint4 b, f32x4 c) {
    return __builtin_amdgcn_mfma_f32_16x16x32_f16(
        __builtin_bit_cast(f16x8, a), __builtin_bit_cast(f16x8, b), c, 0, 0, 0);
}

#define FPOLL(M) __hip_atomic_load(&flags[(M)], __ATOMIC_RELAXED, \
                                   __HIP_MEMORY_SCOPE_AGENT)
#define WAITF(M) { while (FPOLL(M) == 0u) __builtin_amdgcn_s_sleep(2); }
#define SETF(M) __hip_atomic_store(&flags[(M)], 1u, __ATOMIC_RELEASE, \
                                   __HIP_MEMORY_SCOPE_AGENT)

#define BARRIER() asm volatile("s_waitcnt lgkmcnt(0)\n\ts_barrier" ::: "memory")

#define XBIT(PP) ((PP) < 64 ? (unsigned)((xlo >> (PP)) & 1ull) \
                            : (unsigned)((xhi >> ((PP) - 64)) & 1ull))
#define PIDX33(S)                                                          \
    ((S) < 31 ? QMAT + (S)*16 +                                            \
                    (int)((XBIT(4 * (S) + 1) << 3) |                       \
                          (XBIT(4 * (S) + 2) << 2) |                       \
                          (XBIT(4 * (S) + 3) << 1) | XBIT(4 * (S) + 4))    \
              : ((S) == 31 ? 62 * 4 + (int)((XBIT(125) << 1) | XBIT(126))  \
                           : 252 + (int)XBIT(127)))

// fwd step: flag for T+2 polled early (relaxed), checked after compute;
// prefetch issues at step end (in flight across barrier, ~1 step slack).
#define STEP(T, EC, EP, DOPF)                                                 \
    {                                                                         \
        const int p = (T) & 1, np = p ^ 1;                                    \
        const uint4* ewp = (const uint4*)&ewl[p][0] + h * 8;                  \
        uint4 ew_[8];                                                         \
        _Pragma("unroll") for (int q = 0; q < 8; q++) ew_[q] = ewp[q];        \
        int pidx_ = 0;                                                        \
        unsigned fv_ = 1u;                                                    \
        if (DOPF) { pidx_ = PIDX33((T) + 2); fv_ = FPOLL(pidx_); }            \
        __builtin_amdgcn_sched_barrier(0);                                    \
        unsigned mA = pkmax(pkmax(pkmax4(ew_[0]), pkmax4(ew_[1])),            \
                            pkmax(pkmax4(ew_[2]), pkmax4(ew_[3])));           \
        unsigned mB = pkmax(pkmax(pkmax4(ew_[4]), pkmax4(ew_[5])),            \
                            pkmax(pkmax4(ew_[6]), pkmax4(ew_[7])));           \
        unsigned mm = pkmax(mA, mB);                                          \
        auto mr = __builtin_amdgcn_permlane32_swap(mm, mm, false, false);     \
        mm = pkmax(mr[0], mr[1]);                                             \
        mm = pkmax(mm, mm >> 16);                                             \
        unsigned e16 = (mm >> 10) & 31;                                       \
        float f = __uint_as_float((142u - e16) << 23);                        \
        Eacc += (int)e16 - 15;                                                \
        float s0 = 0, s1 = 0, s2 = 0, s3 = 0;                                 \
        float r0 = 0, r1 = 0, r2 = 0, r3 = 0;                                 \
        _Pragma("unroll") for (int q = 0; q < 4; q++) {                       \
            s0 = dot2acc(EC[q].x, ew_[q].x, s0);                              \
            s1 = dot2acc(EC[q].y, ew_[q].y, s1);                              \
            s2 = dot2acc(EC[q].z, ew_[q].z, s2);                              \
            s3 = dot2acc(EC[q].w, ew_[q].w, s3);                              \
        }                                                                     \
        _Pragma("unroll") for (int q = 4; q < 8; q++) {                       \
            r0 = dot2acc(EC[q].x, ew_[q].x, r0);                              \
            r1 = dot2acc(EC[q].y, ew_[q].y, r1);                              \
            r2 = dot2acc(EC[q].z, ew_[q].z, r2);                              \
            r3 = dot2acc(EC[q].w, ew_[q].w, r3);                              \
        }                                                                     \
        float Sh = ((s0 + s1) + (s2 + s3)) + ((r0 + r1) + (r2 + r3));         \
        auto sr = __builtin_amdgcn_permlane32_swap(__float_as_uint(Sh),       \
                                                   __float_as_uint(Sh),       \
                                                   false, false);             \
        float Stot = __uint_as_float(sr[0]) + __uint_as_float(sr[1]);         \
        float pv = Stot * f;                                                  \
        if (DOPF) {                                                           \
            if (fv_ == 0u) WAITF(pidx_);                                      \
            const uint4* pf = (const uint4*)(Pb + (size_t)pidx_ * 32768);     \
            _Pragma("unroll") for (int q = 0; q < 8; q++) EP[q] = pf[q * 256];\
            __builtin_amdgcn_sched_barrier(0);                                \
        }                                                                     \
        v = pv;                                                               \
        ewl[np][j] = (_Float16)pv;                                            \
        BARRIER();                                                            \
    }

__global__ __launch_bounds__(512, 1) void fused(const float* __restrict__ uT,
                                                const float* __restrict__ u1,
                                                const float* __restrict__ x,
                                                const float* __restrict__ lg,
                                                float* __restrict__ ws,
                                                float* __restrict__ out) {
    __shared__ __align__(16) char smem[71168];
    const int blk = blockIdx.x, tid = threadIdx.x;
    const int wave = tid >> 6, lane = tid & 63;
    unsigned* P = (unsigned*)ws;
    unsigned* flags = (unsigned*)ws + FLG_OFF;

    if (blk < 253) {
        // =================== PAIRS role (R15 verbatim + flag) ===============
        if (blk == 252) {  // leftover Ê_126 both combos + LP + out[1]
            float* Zl = (float*)smem;
            float(*bcs)[A_] = (float(*)[A_])(smem + 512);
            const float* u = uT + (size_t)126 * A_ * A_;
            for (int rr = 0; rr < 16; rr += 4) {
#pragma unroll
                for (int qq = 0; qq < 4; qq++) {
                    int r = wave * 16 + rr + qq;
                    float2 uv = *(const float2*)&u[r * A_ + 2 * lane];
                    float ss = wave_sum_bcast(__expf(uv.x) + __expf(uv.y));
                    if (lane == 0) Zl[r] = __logf(ss);
                }
            }
            if (tid < A_) {
                float lv = lg[127 * A_ + tid];
                float sg = 1.f / (1.f + __expf(-lv));
                bcs[1][tid] = sg * 256.f;
                bcs[0][tid] = (1.f - sg) * 256.f;
            }
            __syncthreads();
            unsigned* E0o = P + (size_t)252 * 8192;
            unsigned* E1o = P + (size_t)253 * 8192;
#pragma unroll 4
            for (int it = 0; it < 16; it++) {
                int a = it * 512 + tid;
                int c = a & 3, jl = (a >> 2) & 31, w = (a >> 7) & 3;
                int h = (a >> 9) & 1, q = (a >> 10) & 7;
                int j = 32 * w + jl, i = 32 * h + 4 * q + c;
                float e0 = __expf(u[(2 * i) * A_ + j] - Zl[2 * i]);
                float e1 = __expf(u[(2 * i) * A_ + A_ + j] - Zl[2 * i + 1]);
                E0o[a] = packrtz(e0 * bcs[0][j], e1 * bcs[0][j]);
                E1o[a] = packrtz(e0 * bcs[1][j], e1 * bcs[1][j]);
            }
            if (wave == 0) {
                float a = u1[lane], c = u1[lane + 64];
                float mx = wave_max_bcast(fmaxf(a, c));
                float ss = wave_sum_bcast(__expf(a - mx) + __expf(c - mx));
                float lse = mx + __logf(ss);
                ws[LP_OFF + lane] = a - lse;
                ws[LP_OFF + lane + 64] = c - lse;
                out[B_ * A_ + lane] = a - lse;
                out[B_ * A_ + lane + 64] = c - lse;
            }
            __syncthreads();
            if (tid == 0) { SETF(252); SETF(253); }
            return;
        }
        const int s = blk >> 2, a = (blk >> 1) & 1, bsel = blk & 1;
        _Float16(*E0l)[136] = (_Float16(*)[136])smem;
        _Float16(*E1l)[136] = (_Float16(*)[136])(smem + 34816);
        unsigned(*bcp0)[64] = (unsigned(*)[64])(smem + 69632);
        float(*bc1v)[A_] = (float(*)[A_])(smem + 70144);
        const float* u0 = uT + (size_t)(2 * s) * A_ * A_;
        const float* u1m = uT + (size_t)(2 * s + 1) * A_ * A_;

        if (tid < 64) {
            float la = lg[(2 * s + 1) * A_ + 2 * tid];
            float lb = lg[(2 * s + 1) * A_ + 2 * tid + 1];
            float sa = 1.f / (1.f + __expf(-la));
            float sb = 1.f / (1.f + __expf(-lb));
            bcp0[1][tid] = packrtz(sa, sb);
            bcp0[0][tid] = packrtz(1.f - sa, 1.f - sb);
        } else if (tid < 192) {
            int j = tid - 64;
            float lv = lg[(2 * s + 2) * A_ + j];
            float sg = 1.f / (1.f + __expf(-lv));
            bc1v[1][j] = sg;
            bc1v[0][j] = 1.f - sg;
        }
        {
            const int rbase = wave * 16;
            float2 uv0[16], uv1[16];
#pragma unroll
            for (int rr = 0; rr < 16; rr++)
                uv0[rr] = *(const float2*)&u0[(rbase + rr) * A_ + 2 * lane];
#pragma unroll
            for (int rr = 0; rr < 16; rr++)
                uv1[rr] = *(const float2*)&u1m[(rbase + rr) * A_ + 2 * lane];
            __builtin_amdgcn_sched_barrier(0);
#pragma unroll
            for (int rr = 0; rr < 16; rr++) {
                int r = rbase + rr;
                float e0 = __expf(uv0[rr].x), e1 = __expf(uv0[rr].y);
                float rs = __builtin_amdgcn_rcpf(wave_sum_bcast(e0 + e1));
                *(unsigned*)&E0l[r][2 * lane] = packrtz(e0 * rs, e1 * rs);
            }
#pragma unroll
            for (int rr = 0; rr < 16; rr++) {
                int m = rbase + rr;
                float e0 = __expf(uv1[rr].x), e1 = __expf(uv1[rr].y);
                float rs = __builtin_amdgcn_rcpf(wave_sum_bcast(e0 + e1));
                E1l[2 * lane][m] = (_Float16)(e0 * rs);
                E1l[2 * lane + 1][m] = (_Float16)(e1 * rs);
            }
        }
        __syncthreads();

        const int lo16 = lane & 15, g = lane >> 4;
        unsigned* Pg = P + (size_t)(s * 4 + a * 2 + bsel) * 8192;
        const int mq = wave;
        uint4 Af[4];
#pragma unroll
        for (int kc = 0; kc < 4; kc++) {
            uint4 av = *(const uint4*)&E0l[16 * mq + lo16][32 * kc + 8 * g];
            uint4 bp = *(const uint4*)&bcp0[a][16 * kc + 4 * g];
            av.x = pkmul(av.x, bp.x);
            av.y = pkmul(av.y, bp.y);
            av.z = pkmul(av.z, bp.z);
            av.w = pkmul(av.w, bp.w);
            Af[kc] = av;
        }
        f32x4 acc[8];
#pragma unroll
        for (int nq = 0; nq < 8; nq++) {
            acc[nq] = (f32x4){0.f, 0.f, 0.f, 0.f};
#pragma unroll
            for (int kc = 0; kc < 4; kc++)
                acc[nq] = mfma16(
                    Af[kc],
                    *(const uint4*)&E1l[16 * nq + lo16][32 * kc + 8 * g],
                    acc[nq]);
        }
#pragma unroll
        for (int nq = 0; nq < 8; nq++) {
            int j = 16 * nq + lo16;
            int jpart = (j >> 5) * 128 + (j & 31) * 4;
            float mf = bc1v[bsel][j] * 256.f;
            unsigned p0 = packrtz(acc[nq][0] * mf, acc[nq][1] * mf);
            unsigned p1 = packrtz(acc[nq][2] * mf, acc[nq][3] * mf);
            int i0 = 8 * mq + 2 * g;
            int i1 = i0 + 1;
            Pg[((i0 >> 2) & 7) * 1024 + (i0 >> 5) * 512 + jpart + (i0 & 3)] = p0;
            Pg[((i1 >> 2) & 7) * 1024 + (i1 >> 5) * 512 + jpart + (i1 & 3)] = p1;
        }
        __syncthreads();
        if (tid == 0) SETF(s * 4 + a * 2 + bsel);
        return;
    }

    if (blk < 501) {
        // =================== QUADS role: 2 variants per block ===============
        const int qb = blk - 253;
        const int S = qb >> 3, inn = qb & 7;   // inn = b*4 + c*2 + d
        const int bb = inn >> 2;
        const int matB = 8 * S + 4 + (inn & 3);
        const int matA0 = 8 * S + bb;          // a=0
        const int matA1 = 8 * S + 2 + bb;      // a=1
        _Float16(*Al)[136] = (_Float16(*)[136])smem;
        _Float16(*Bl)[136] = (_Float16(*)[136])(smem + 34816);
        const unsigned* PB = P + (size_t)matB * 8192;
        unsigned* Q0 = P + (size_t)(QMAT + S * 16 + inn) * 8192;
        unsigned* Q1 = P + (size_t)(QMAT + S * 16 + 8 + inn) * 8192;
        const int lo16 = lane & 15, g = lane >> 4;
        const float mf = 1.f / 256.f;
        const int mq = wave;

        WAITF(matB);
        WAITF(matA0);
        {
            const unsigned* PA = P + (size_t)matA0 * 8192;
            unsigned v1s[16], v2s[16];
#pragma unroll
            for (int it = 0; it < 16; it++) v1s[it] = PA[it * 512 + tid];
#pragma unroll
            for (int it = 0; it < 16; it++) v2s[it] = PB[it * 512 + tid];
            __builtin_amdgcn_sched_barrier(0);
#pragma unroll
            for (int it = 0; it < 16; it++) {
                int a = it * 512 + tid;
                int c = a & 3, jl = (a >> 2) & 31, w = (a >> 7) & 3;
                int h = (a >> 9) & 1, q = (a >> 10) & 7;
                int i = 32 * h + 4 * q + c, j = 32 * w + jl;
                h2 p = __builtin_bit_cast(h2, v1s[it]);
                Al[2 * i][j] = p[0];
                Al[2 * i + 1][j] = p[1];
                *(unsigned*)&Bl[j][2 * i] = v2s[it];
            }
        }
        __syncthreads();
#pragma unroll 1
        for (int phase = 0; phase < 2; phase++) {
            unsigned* Q = phase ? Q1 : Q0;
            uint4 Af[4];
#pragma unroll
            for (int kc = 0; kc < 4; kc++)
                Af[kc] = *(const uint4*)&Al[16 * mq + lo16][32 * kc + 8 * g];
            f32x4 acc[8];
#pragma unroll
            for (int nq = 0; nq < 8; nq++) {
                acc[nq] = (f32x4){0.f, 0.f, 0.f, 0.f};
#pragma unroll
                for (int kc = 0; kc < 4; kc++)
                    acc[nq] = mfma16(
                        Af[kc],
                        *(const uint4*)&Bl[16 * nq + lo16][32 * kc + 8 * g],
                        acc[nq]);
            }
#pragma unroll
            for (int nq = 0; nq < 8; nq++) {
                int j = 16 * nq + lo16;
                int jpart = (j >> 5) * 128 + (j & 31) * 4;
                unsigned p0 = packrtz(acc[nq][0] * mf, acc[nq][1] * mf);
                unsigned p1 = packrtz(acc[nq][2] * mf, acc[nq][3] * mf);
                int i0 = 8 * mq + 2 * g;
                int i1 = i0 + 1;
                Q[((i0 >> 2) & 7) * 1024 + (i0 >> 5) * 512 + jpart + (i0 & 3)] = p0;
                Q[((i1 >> 2) & 7) * 1024 + (i1 >> 5) * 512 + jpart + (i1 & 3)] = p1;
            }
            __syncthreads();
            if (tid == 0) SETF(QMAT + S * 16 + phase * 8 + inn);
            if (phase == 0) {  // restage Al from matA1 (Bl reused)
                WAITF(matA1);
                const unsigned* PA = P + (size_t)matA1 * 8192;
                unsigned v1s[16];
#pragma unroll
                for (int it = 0; it < 16; it++) v1s[it] = PA[it * 512 + tid];
#pragma unroll
                for (int it = 0; it < 16; it++) {
                    int a = it * 512 + tid;
                    int c = a & 3;
                    int h = (a >> 9) & 1, q = (a >> 10) & 7;
                    int jl = (a >> 2) & 31, w = (a >> 7) & 3;
                    int i = 32 * h + 4 * q + c, j = 32 * w + jl;
                    h2 p = __builtin_bit_cast(h2, v1s[it]);
                    Al[2 * i][j] = p[0];
                    Al[2 * i + 1][j] = p[1];
                }
                __syncthreads();
            }
        }
        return;
    }

    // =================== FWD role: 64 chains, 33 steps =====================
    {
        const int b = blk - 501;
        const int w = wave & 3;            // waves 4-7 mirror 0-3
        const int h = lane >> 5, jl = lane & 31;
        const int j = 32 * w + jl;
        _Float16(*ewl)[A_] = (_Float16(*)[A_])smem;
        float* sums = (float*)(smem + 512);

        const char* Pb = (const char*)ws + (size_t)h * 2048 + w * 512 + jl * 16;
        const float* LP = ws + LP_OFF;

        unsigned long long xlo = __ballot(x[b * D_ + lane] != 0.f);
        unsigned long long xhi = __ballot(x[b * D_ + 64 + lane] != 0.f);

        WAITF(252);   // leftover block: LP ready
        float ll = lg[j];
        float sp = (ll > 0.f) ? (ll + log1pf(__expf(-ll))) : log1pf(__expf(ll));
        float xv0 = x[b * D_];
        float vlog = LP[j] + ((xv0 != 0.f) ? (ll - sp) : (-sp));
        float mw = wave_max_bcast(vlog);
        sums[w] = mw;
        BARRIER();
        float Phi0 = fmaxf(fmaxf(sums[0], sums[1]), fmaxf(sums[2], sums[3]));
        float v = __expf(vlog - Phi0);
        ewl[0][j] = (_Float16)v;
        int Eacc = 0;

        uint4 E0[8], E1[8], E2[8];
        {
            int i0 = PIDX33(0), i1 = PIDX33(1);
            WAITF(i0);
            WAITF(i1);
            const uint4* p0 = (const uint4*)(Pb + (size_t)i0 * 32768);
            const uint4* p1 = (const uint4*)(Pb + (size_t)i1 * 32768);
#pragma unroll
            for (int q = 0; q < 8; q++) {
                E0[q] = p0[q * 256];
                E1[q] = p1[q * 256];
            }
            __builtin_amdgcn_sched_barrier(0);
        }
        BARRIER();

        for (int t = 0; t < 30; t += 3) {
            STEP(t + 0, E0, E2, 1)
            STEP(t + 1, E1, E0, 1)
            STEP(t + 2, E2, E1, 1)
        }
        STEP(30, E0, E2, 1)
        STEP(31, E1, E0, 0)
        STEP(32, E2, E1, 0)

        float sw = wave_sum_bcast(v) * 0.5f;
        sums[w] = sw;
        BARRIER();
        float tot = (sums[0] + sums[1]) + (sums[2] + sums[3]);
        float L = Phi0 + 0.69314718055994531f * (float)(Eacc - 264) + __logf(tot);
        if (tid < A_) out[b * A_ + tid] = L;
    }
}

extern "C" void kernel_launch(void* const* d_in, const int* in_sizes, int n_in,
                              void* d_out, int out_size, void* d_ws, size_t ws_size,
                              hipStream_t stream) {
    const float* x = (const float*)d_in[0];    // [B,D]
    const float* u1 = (const float*)d_in[1];   // [1,1,1,A]
    const float* uT = (const float*)d_in[2];   // [D-1,A,A]
    const float* lg = (const float*)d_in[3];   // [1,D,1,A]
    float* ws = (float*)d_ws;                  // ~24.6 MB used
    float* out = (float*)d_out;

    // zero the flag words (harness poisons ws each iteration)
    hipMemsetAsync((char*)d_ws + (size_t)FLG_OFF * 4, 0, 752 * 4, stream);
    fused<<<dim3(565), dim3(512), 0, stream>>>(uT, u1, x, lg, ws, out);
}